// Round 3
// baseline (702.472 us; speedup 1.0000x reference)
//
#include <hip/hip_runtime.h>

// Problem constants
#define B_   8
#define SQ_  1024
#define SK_  1024
#define D_   512
#define H_   8
#define DFF_ 2048
#define L_   2
#define HD_  64
#define M_   8192   // B*SQ = B*SK rows

typedef __bf16 bf16;
using bf16x8 = __attribute__((ext_vector_type(8))) __bf16;
using f32x4  = __attribute__((ext_vector_type(4))) float;

__device__ inline f32x4 mfma16(bf16x8 a, bf16x8 b, f32x4 c) {
  return __builtin_amdgcn_mfma_f32_16x16x32_bf16(a, b, c, 0, 0, 0);
}

// ---------------------------------------------------------------------------
// Batched 32x32 tiled transpose + fp32->bf16: out[l][c][r] = (bf16)in[l][r][c]
// grid: (C/32, R/32, L), block 256
// ---------------------------------------------------------------------------
__global__ __launch_bounds__(256) void transpose_k(
    const float* __restrict__ in, bf16* __restrict__ out, int R, int C) {
  __shared__ bf16 tile[32][33];
  const float* inp  = in  + (size_t)blockIdx.z * R * C;
  bf16*        outp = out + (size_t)blockIdx.z * R * C;
  int c0 = blockIdx.x * 32, r0 = blockIdx.y * 32;
  int tx = threadIdx.x & 31, ty = threadIdx.x >> 5;  // ty in 0..7
#pragma unroll
  for (int i = 0; i < 32; i += 8)
    tile[ty + i][tx] = (bf16)inp[(size_t)(r0 + ty + i) * C + c0 + tx];
  __syncthreads();
#pragma unroll
  for (int i = 0; i < 32; i += 8)
    outp[(size_t)(c0 + ty + i) * R + r0 + tx] = tile[tx][ty + i];
}

// fp32 -> bf16 elementwise (4 per thread)
__global__ __launch_bounds__(256) void f2b_k(const float* __restrict__ in,
                                             bf16* __restrict__ out, int n) {
  int i = (blockIdx.x * 256 + threadIdx.x) * 4;
  if (i < n) {
    float4 v = *(const float4*)&in[i];
    out[i] = (bf16)v.x; out[i + 1] = (bf16)v.y;
    out[i + 2] = (bf16)v.z; out[i + 3] = (bf16)v.w;
  }
}

// ---------------------------------------------------------------------------
// GEMM: C[M,N] = A[M,K] (bf16, row-major) * Bt[N,K]^T (bf16) + bias(f32)
// 128x128 tile, 4 waves (2x2), each wave 64x64 via 4x4 16x16x32 MFMAs.
// epilogue: optional exact GELU; writes bf16 (Cb) and/or f32 (Cf).
// grid: (M/128, N/128), block 256
// ---------------------------------------------------------------------------
__global__ __launch_bounds__(256) void gemm_k(
    const bf16* __restrict__ A, const bf16* __restrict__ Bt,
    const float* __restrict__ bias, bf16* __restrict__ Cb,
    float* __restrict__ Cf, int Nsz, int Ksz, int gelu) {
  __shared__ bf16 As[128 * 40];  // k-stride padded 32->40 (2-way bank alias: free)
  __shared__ bf16 Bs[128 * 40];
  const int tid = threadIdx.x;
  const int m0 = blockIdx.x * 128, n0 = blockIdx.y * 128;
  const int w = tid >> 6, lane = tid & 63, quad = lane >> 4, l16 = lane & 15;
  const int wm = (w & 1) << 6, wn = (w >> 1) << 6;
  const int row0 = tid >> 2, koff = (tid & 3) << 3;  // 512 16B chunks, 2/thread
  const int row1 = row0 + 64;
  f32x4 acc[4][4] = {};
  for (int k0 = 0; k0 < Ksz; k0 += 32) {
    __syncthreads();
    *(uint4*)&As[row0 * 40 + koff] = *(const uint4*)&A [(size_t)(m0 + row0) * Ksz + k0 + koff];
    *(uint4*)&As[row1 * 40 + koff] = *(const uint4*)&A [(size_t)(m0 + row1) * Ksz + k0 + koff];
    *(uint4*)&Bs[row0 * 40 + koff] = *(const uint4*)&Bt[(size_t)(n0 + row0) * Ksz + k0 + koff];
    *(uint4*)&Bs[row1 * 40 + koff] = *(const uint4*)&Bt[(size_t)(n0 + row1) * Ksz + k0 + koff];
    __syncthreads();
    bf16x8 af[4], bfr[4];
#pragma unroll
    for (int i = 0; i < 4; i++) af[i]  = *(const bf16x8*)&As[(wm + i * 16 + l16) * 40 + quad * 8];
#pragma unroll
    for (int i = 0; i < 4; i++) bfr[i] = *(const bf16x8*)&Bs[(wn + i * 16 + l16) * 40 + quad * 8];
#pragma unroll
    for (int mi = 0; mi < 4; mi++)
#pragma unroll
      for (int ni = 0; ni < 4; ni++)
        acc[mi][ni] = mfma16(af[mi], bfr[ni], acc[mi][ni]);
  }
  // epilogue. C/D layout: col = l16 (+16*ni), row = quad*4 + r (+16*mi)
#pragma unroll
  for (int mi = 0; mi < 4; mi++)
#pragma unroll
    for (int ni = 0; ni < 4; ni++) {
      int col = n0 + wn + ni * 16 + l16;
      float bv = bias[col];
#pragma unroll
      for (int r = 0; r < 4; r++) {
        int row = m0 + wm + mi * 16 + quad * 4 + r;
        float x = acc[mi][ni][r] + bv;
        if (gelu) x = 0.5f * x * (1.0f + erff(x * 0.70710678118f));
        size_t idx = (size_t)row * Nsz + col;
        if (Cb) Cb[idx] = (bf16)x;
        if (Cf) Cf[idx] = x;
      }
    }
}

// ---------------------------------------------------------------------------
// vh [B*SK, D] (head h at cols h*64..) -> vt [B,H,HD,SK]  (per-head V^T)
// grid: (SK/64, B*H), block 256
// ---------------------------------------------------------------------------
__global__ __launch_bounds__(256) void vtrans_k(const bf16* __restrict__ vh,
                                                bf16* __restrict__ vt) {
  __shared__ bf16 sm[64][72];
  int kt = blockIdx.x, bh = blockIdx.y;
  int b = bh >> 3, h = bh & 7;
  int tid = threadIdx.x;
  for (int c = tid; c < 512; c += 256) {
    int key = c >> 3, off = (c & 7) * 8;
    *(uint4*)&sm[key][off] =
        *(const uint4*)&vh[(size_t)(b * SK_ + kt * 64 + key) * D_ + h * 64 + off];
  }
  __syncthreads();
  for (int c = tid; c < 512; c += 256) {
    int hd = c >> 3, koff = (c & 7) * 8;
    bf16 tmp[8];
#pragma unroll
    for (int j = 0; j < 8; j++) tmp[j] = sm[koff + j][hd];
    *(uint4*)&vt[(size_t)(bh * 64 + hd) * SK_ + kt * 64 + koff] = *(uint4*)tmp;
  }
}

// ---------------------------------------------------------------------------
// Flash attention with Realformer prev-score recompute.
// scores = eff1*(Q1 K1^T) [+ eff0*(Q0 K0^T) if li>0]; online softmax; O = P V.
// grid: (SQ/64, B*H), block 256 (4 waves, 16 Q-rows each)
// ---------------------------------------------------------------------------
__global__ __launch_bounds__(256) void attn_k(
    const bf16* __restrict__ qh, const bf16* __restrict__ kh,
    const bf16* __restrict__ vt, const bf16* __restrict__ qh0,
    const bf16* __restrict__ kh0, const float* __restrict__ scale,
    const float* __restrict__ extra, int li, bf16* __restrict__ ctx) {
  __shared__ bf16 Ks[64 * 72];
  __shared__ bf16 K0s[64 * 72];
  __shared__ bf16 Vs[64 * 72];   // V^T tile: [hd][key]
  __shared__ bf16 Ps[4][16 * 72];
  int qt = blockIdx.x, bh = blockIdx.y;
  int b = bh >> 3, h = bh & 7;
  int tid = threadIdx.x, w = tid >> 6, lane = tid & 63;
  int quad = lane >> 4, l16 = lane & 15;
  float eff1 = scale[li] * fminf(fmaxf(extra[li], 0.01f), 50.0f);
  float eff0 = 0.f;
  if (li > 0)
    eff0 = scale[li - 1] * fminf(fmaxf(extra[li - 1], 0.01f), 50.0f);
  // Q fragments (A-layout: m=l16, k=quad*8+j), held in regs for whole kernel
  int qrow = b * SQ_ + qt * 64 + w * 16 + l16;
  const bf16* qp = qh + (size_t)qrow * D_ + h * 64 + quad * 8;
  bf16x8 aq[2] = { *(const bf16x8*)qp, *(const bf16x8*)(qp + 32) };
  bf16x8 aq0[2] = {};
  if (li > 0) {
    const bf16* qp0 = qh0 + (size_t)qrow * D_ + h * 64 + quad * 8;
    aq0[0] = *(const bf16x8*)qp0; aq0[1] = *(const bf16x8*)(qp0 + 32);
  }
  float mrun[4], lrun[4];
  f32x4 o[4] = {};
#pragma unroll
  for (int r = 0; r < 4; r++) { mrun[r] = -1e30f; lrun[r] = 0.f; }

  for (int kt = 0; kt < SK_ / 64; kt++) {
    __syncthreads();
    for (int c = tid; c < 512; c += 256) {
      int key = c >> 3, off = (c & 7) * 8;
      size_t gk = (size_t)(b * SK_ + kt * 64 + key) * D_ + h * 64 + off;
      *(uint4*)&Ks[key * 72 + off] = *(const uint4*)&kh[gk];
      if (li > 0) *(uint4*)&K0s[key * 72 + off] = *(const uint4*)&kh0[gk];
      *(uint4*)&Vs[key * 72 + off] =
          *(const uint4*)&vt[(size_t)(bh * 64 + key) * SK_ + kt * 64 + off];
    }
    __syncthreads();
    // S tile 16x64 per wave
    f32x4 s[4];
#pragma unroll
    for (int ni = 0; ni < 4; ni++) {
      f32x4 t = {};
      const bf16* kp = &Ks[(ni * 16 + l16) * 72 + quad * 8];
      t = mfma16(aq[0], *(const bf16x8*)kp, t);
      t = mfma16(aq[1], *(const bf16x8*)(kp + 32), t);
      if (li > 0) {
        f32x4 t0 = {};
        const bf16* kp0 = &K0s[(ni * 16 + l16) * 72 + quad * 8];
        t0 = mfma16(aq0[0], *(const bf16x8*)kp0, t0);
        t0 = mfma16(aq0[1], *(const bf16x8*)(kp0 + 32), t0);
#pragma unroll
        for (int r = 0; r < 4; r++) s[ni][r] = eff1 * t[r] + eff0 * t0[r];
      } else {
#pragma unroll
        for (int r = 0; r < 4; r++) s[ni][r] = eff1 * t[r];
      }
    }
    // online softmax (row = quad*4+r; row's cols live across the quad's 16 lanes)
#pragma unroll
    for (int r = 0; r < 4; r++) {
      float mt = fmaxf(fmaxf(s[0][r], s[1][r]), fmaxf(s[2][r], s[3][r]));
#pragma unroll
      for (int msk = 1; msk < 16; msk <<= 1) mt = fmaxf(mt, __shfl_xor(mt, msk));
      float mnew = fmaxf(mrun[r], mt);
      float alpha = __expf(mrun[r] - mnew);
      float ls = 0.f;
#pragma unroll
      for (int ni = 0; ni < 4; ni++) {
        float p = __expf(s[ni][r] - mnew);
        s[ni][r] = p;
        ls += p;
      }
#pragma unroll
      for (int msk = 1; msk < 16; msk <<= 1) ls += __shfl_xor(ls, msk);
      lrun[r] = lrun[r] * alpha + ls;
      mrun[r] = mnew;
#pragma unroll
      for (int ni = 0; ni < 4; ni++) o[ni][r] *= alpha;
    }
    // P: C-layout -> LDS row-major [qrow][key] -> A-layout frags
#pragma unroll
    for (int ni = 0; ni < 4; ni++)
#pragma unroll
      for (int r = 0; r < 4; r++)
        Ps[w][(quad * 4 + r) * 72 + ni * 16 + l16] = (bf16)s[ni][r];
    __syncthreads();
#pragma unroll
    for (int kk = 0; kk < 2; kk++) {
      bf16x8 ap = *(const bf16x8*)&Ps[w][l16 * 72 + quad * 8 + kk * 32];
#pragma unroll
      for (int ni = 0; ni < 4; ni++) {
        bf16x8 bv = *(const bf16x8*)&Vs[(ni * 16 + l16) * 72 + quad * 8 + kk * 32];
        o[ni] = mfma16(ap, bv, o[ni]);
      }
    }
  }
  // epilogue: O /= l, write ctx bf16 [B*SQ, D]
#pragma unroll
  for (int ni = 0; ni < 4; ni++)
#pragma unroll
    for (int r = 0; r < 4; r++) {
      int row = b * SQ_ + qt * 64 + w * 16 + quad * 4 + r;
      ctx[(size_t)row * D_ + h * 64 + ni * 16 + l16] = (bf16)(o[ni][r] / lrun[r]);
    }
}

// ---------------------------------------------------------------------------
// Gated residual + post-LN: x = cur + softplus(gate)*add; y = LN(x)*g + b
// writes fp32 (residual stream / final out) and bf16 (next matmul input)
// grid: M_ rows, block 256 (2 cols/thread)
// ---------------------------------------------------------------------------
__global__ __launch_bounds__(256) void ln_k(
    const float* __restrict__ cur_in, const float* __restrict__ add,
    const float* __restrict__ gate, const float* __restrict__ g,
    const float* __restrict__ bb, float* __restrict__ outf,
    bf16* __restrict__ outb) {
  int row = blockIdx.x, tid = threadIdx.x;
  float gv = gate[0];
  float sp = gv > 20.f ? gv : log1pf(expf(gv));
  size_t base = (size_t)row * D_;
  int c0 = tid * 2;
  float2 c2 = *(const float2*)&cur_in[base + c0];
  float2 a2 = *(const float2*)&add[base + c0];
  float x0 = c2.x + sp * a2.x, x1 = c2.y + sp * a2.y;
  float s = x0 + x1, s2 = x0 * x0 + x1 * x1;
#pragma unroll
  for (int m = 1; m < 64; m <<= 1) {
    s += __shfl_xor(s, m);
    s2 += __shfl_xor(s2, m);
  }
  __shared__ float sa[4], sb[4];
  int w = tid >> 6;
  if ((tid & 63) == 0) { sa[w] = s; sb[w] = s2; }
  __syncthreads();
  s = sa[0] + sa[1] + sa[2] + sa[3];
  s2 = sb[0] + sb[1] + sb[2] + sb[3];
  float mu = s * (1.f / D_);
  float var = s2 * (1.f / D_) - mu * mu;
  float rs = rsqrtf(var + 1e-5f);
  float y0 = (x0 - mu) * rs * g[c0] + bb[c0];
  float y1 = (x1 - mu) * rs * g[c0 + 1] + bb[c0 + 1];
  if (outf) { float2 y; y.x = y0; y.y = y1; *(float2*)&outf[base + c0] = y; }
  if (outb) { outb[base + c0] = (bf16)y0; outb[base + c0 + 1] = (bf16)y1; }
}

// ---------------------------------------------------------------------------
extern "C" void kernel_launch(void* const* d_in, const int* in_sizes, int n_in,
                              void* d_out, int out_size, void* d_ws,
                              size_t ws_size, hipStream_t stream) {
  const float* qin = (const float*)d_in[0];
  const float* kin = (const float*)d_in[1];
  const float* vin = (const float*)d_in[2];
  const float* WQ  = (const float*)d_in[3];
  const float* bQ  = (const float*)d_in[4];
  const float* WK  = (const float*)d_in[5];
  const float* bK  = (const float*)d_in[6];
  const float* WV  = (const float*)d_in[7];
  const float* bV  = (const float*)d_in[8];
  const float* WO  = (const float*)d_in[9];
  const float* bO  = (const float*)d_in[10];
  const float* Wf1 = (const float*)d_in[11];
  const float* bf1 = (const float*)d_in[12];
  const float* Wf2 = (const float*)d_in[13];
  const float* bf2 = (const float*)d_in[14];
  const float* l1g = (const float*)d_in[15];
  const float* l1b = (const float*)d_in[16];
  const float* l2g = (const float*)d_in[17];
  const float* l2b = (const float*)d_in[18];
  const float* sc  = (const float*)d_in[19];
  const float* ex  = (const float*)d_in[20];
  const float* ga  = (const float*)d_in[21];
  const float* gf  = (const float*)d_in[22];

  char* p = (char*)d_ws;
  auto alloc = [&](size_t bytes) {
    void* r = (void*)p;
    p += (bytes + 255) & ~(size_t)255;
    return r;
  };
  bf16* WQt  = (bf16*)alloc((size_t)L_ * D_ * D_ * 2);
  bf16* WKt  = (bf16*)alloc((size_t)L_ * D_ * D_ * 2);
  bf16* WVt  = (bf16*)alloc((size_t)L_ * D_ * D_ * 2);
  bf16* WOt  = (bf16*)alloc((size_t)L_ * D_ * D_ * 2);
  bf16* Wf1t = (bf16*)alloc((size_t)L_ * D_ * DFF_ * 2);
  bf16* Wf2t = (bf16*)alloc((size_t)L_ * D_ * DFF_ * 2);
  float* cur  = (float*)alloc((size_t)M_ * D_ * 4);
  bf16* curb  = (bf16*)alloc((size_t)M_ * D_ * 2);
  bf16* qb    = (bf16*)alloc((size_t)M_ * D_ * 2);
  bf16* kb    = (bf16*)alloc((size_t)M_ * D_ * 2);
  bf16* vb    = (bf16*)alloc((size_t)M_ * D_ * 2);
  bf16* qhl[2], *khl[2];
  qhl[0] = (bf16*)alloc((size_t)M_ * D_ * 2);
  qhl[1] = (bf16*)alloc((size_t)M_ * D_ * 2);
  khl[0] = (bf16*)alloc((size_t)M_ * D_ * 2);
  khl[1] = (bf16*)alloc((size_t)M_ * D_ * 2);
  bf16* vh   = (bf16*)alloc((size_t)M_ * D_ * 2);
  bf16* vt   = (bf16*)alloc((size_t)M_ * D_ * 2);
  bf16* ctx  = (bf16*)alloc((size_t)M_ * D_ * 2);
  float* proj = (float*)alloc((size_t)M_ * D_ * 4);
  bf16* ffmid = (bf16*)alloc((size_t)M_ * DFF_ * 2);
  float* ffout = (float*)alloc((size_t)M_ * D_ * 4);

  // one-time (per launch) prep: transpose+downcast weights, downcast q/k/v
  transpose_k<<<dim3(D_ / 32, D_ / 32, L_), 256, 0, stream>>>(WQ, WQt, D_, D_);
  transpose_k<<<dim3(D_ / 32, D_ / 32, L_), 256, 0, stream>>>(WK, WKt, D_, D_);
  transpose_k<<<dim3(D_ / 32, D_ / 32, L_), 256, 0, stream>>>(WV, WVt, D_, D_);
  transpose_k<<<dim3(D_ / 32, D_ / 32, L_), 256, 0, stream>>>(WO, WOt, D_, D_);
  transpose_k<<<dim3(DFF_ / 32, D_ / 32, L_), 256, 0, stream>>>(Wf1, Wf1t, D_, DFF_);
  transpose_k<<<dim3(D_ / 32, DFF_ / 32, L_), 256, 0, stream>>>(Wf2, Wf2t, DFF_, D_);
  f2b_k<<<(M_ * D_) / 1024, 256, 0, stream>>>(qin, qb, M_ * D_);
  f2b_k<<<(M_ * D_) / 1024, 256, 0, stream>>>(kin, kb, M_ * D_);
  f2b_k<<<(M_ * D_) / 1024, 256, 0, stream>>>(vin, vb, M_ * D_);

  for (int li = 0; li < L_; li++) {
    const bf16* aQ = (li == 0) ? qb : curb;
    gemm_k<<<dim3(M_ / 128, D_ / 128), 256, 0, stream>>>(
        aQ, WQt + (size_t)li * D_ * D_, bQ + li * D_, qhl[li], nullptr, D_, D_, 0);
    gemm_k<<<dim3(M_ / 128, D_ / 128), 256, 0, stream>>>(
        kb, WKt + (size_t)li * D_ * D_, bK + li * D_, khl[li], nullptr, D_, D_, 0);
    gemm_k<<<dim3(M_ / 128, D_ / 128), 256, 0, stream>>>(
        vb, WVt + (size_t)li * D_ * D_, bV + li * D_, vh, nullptr, D_, D_, 0);
    vtrans_k<<<dim3(SK_ / 64, B_ * H_), 256, 0, stream>>>(vh, vt);
    attn_k<<<dim3(SQ_ / 64, B_ * H_), 256, 0, stream>>>(
        qhl[li], khl[li], vt, qhl[0], khl[0], sc, ex, li, ctx);
    gemm_k<<<dim3(M_ / 128, D_ / 128), 256, 0, stream>>>(
        ctx, WOt + (size_t)li * D_ * D_, bO + li * D_, nullptr, proj, D_, D_, 0);
    ln_k<<<M_, 256, 0, stream>>>((li == 0) ? qin : cur, proj, ga + li,
                                 l1g + li * D_, l1b + li * D_, cur, curb);
    gemm_k<<<dim3(M_ / 128, DFF_ / 128), 256, 0, stream>>>(
        curb, Wf1t + (size_t)li * D_ * DFF_, bf1 + li * DFF_, ffmid, nullptr,
        DFF_, D_, 1);
    gemm_k<<<dim3(M_ / 128, D_ / 128), 256, 0, stream>>>(
        ffmid, Wf2t + (size_t)li * DFF_ * D_, bf2 + li * D_, nullptr, ffout,
        D_, DFF_, 0);
    // Final layer: single LN writing fp32 straight to d_out (the round-2 bug
    // was a second ln_k call re-reading the already-overwritten `cur`).
    ln_k<<<M_, 256, 0, stream>>>(cur, ffout, gf + li, l2g + li * D_,
                                 l2b + li * D_,
                                 (li == L_ - 1) ? (float*)d_out : cur,
                                 (li == L_ - 1) ? nullptr : curb);
  }
}